// Round 8
// baseline (117.365 us; speedup 1.0000x reference)
//
#include <hip/hip_runtime.h>
#include <math.h>

#define NN 8192      // nodes
#define FH 128       // hidden
#define NC 16        // clusters
#define HP 132       // padded LDS row
#define CHUNK 32     // nodes per block in node phase
#define NBLK 256
#define NTHR 256

// ---------------- workspace layout (floats) ----------------
// zeroed region (by k_zero):
#define WS_CNT    0         // [8192]
#define WS_AGG4   8192      // [32768]
#define WS_OADJ   40960     // 4 x 256 replicas
#define WS_CA     41984     // 16 x 16
#define WS_CS     42240     // 16 x 16
#define WS_BAR    42496     // [128] ints
#define WS_ZERO_FLOATS 42624
// slabs (fully overwritten every call, no zeroing needed):
#define WS_ORAWS  42624     // [256][2048] per-block oraw partials
#define WS_SSS    566912    // [256][256]  per-block ss partials
#define WS_ORAWF  632448    // [2048] reduced oraw
#define WS_SSF    634496    // [256]  reduced ss
// total 634752 floats = 2.54 MB (ws proven >= 4.4 MB in round 1)

#define BAR_ARRIVE 0
#define BAR_GEN    64
#define BAR_DONE   96

// ---------------- K0: zero accumulators + barrier state ----------------
__global__ __launch_bounds__(256) void k_zero(float4* __restrict__ ws) {
    int i = blockIdx.x * blockDim.x + threadIdx.x;
    if (i < WS_ZERO_FLOATS / 4) ws[i] = make_float4(0.f, 0.f, 0.f, 0.f);
}

// ---- software grid barrier: relaxed spin, fences only at entry/exit ----
__device__ __forceinline__ void gbar(int* bar) {
    __syncthreads();
    if (threadIdx.x == 0) {
        __threadfence();                   // release this block's writes
        int g = __hip_atomic_load(&bar[BAR_GEN], __ATOMIC_RELAXED,
                                  __HIP_MEMORY_SCOPE_AGENT);
        int prev = __hip_atomic_fetch_add(&bar[BAR_ARRIVE], 1, __ATOMIC_RELAXED,
                                          __HIP_MEMORY_SCOPE_AGENT);
        if (prev == NBLK - 1) {
            __hip_atomic_store(&bar[BAR_ARRIVE], 0, __ATOMIC_RELAXED,
                               __HIP_MEMORY_SCOPE_AGENT);
            __threadfence();               // order arrivals -> gen flip
            __hip_atomic_fetch_add(&bar[BAR_GEN], 1, __ATOMIC_RELAXED,
                                   __HIP_MEMORY_SCOPE_AGENT);
        } else {
            while (__hip_atomic_load(&bar[BAR_GEN], __ATOMIC_RELAXED,
                                     __HIP_MEMORY_SCOPE_AGENT) == g)
                __builtin_amdgcn_s_sleep(4);
        }
        __threadfence();                   // acquire other blocks' writes
    }
    __syncthreads();
}

__device__ __forceinline__ float selu_f(float x) {
    const float a = 1.6732632423543772f, sc = 1.0507009873554805f;
    return sc * (x > 0.0f ? x : a * (expf(x) - 1.0f));
}

__device__ __forceinline__ float bsum256(float v, float* sh) {
    #pragma unroll
    for (int o = 32; o; o >>= 1) v += __shfl_down(v, o, 64);
    if ((threadIdx.x & 63) == 0) sh[threadIdx.x >> 6] = v;
    __syncthreads();
    float r = sh[0] + sh[1] + sh[2] + sh[3];
    __syncthreads();
    return r;
}
__device__ __forceinline__ float bmax256(float v, float* sh) {
    #pragma unroll
    for (int o = 32; o; o >>= 1) v = fmaxf(v, __shfl_down(v, o, 64));
    if ((threadIdx.x & 63) == 0) sh[threadIdx.x >> 6] = v;
    __syncthreads();
    float r = fmaxf(fmaxf(sh[0], sh[1]), fmaxf(sh[2], sh[3]));
    __syncthreads();
    return r;
}

__global__ __launch_bounds__(NTHR) void k_mega(
    const float* __restrict__ x, const float* __restrict__ W1,
    const float* __restrict__ b1, const float* __restrict__ Wp,
    const float* __restrict__ bp, const int* __restrict__ ei,
    float* __restrict__ ws, float* __restrict__ s_out,
    float* __restrict__ d_out, int E)
{
    float* cnt   = ws + WS_CNT;
    float* agg4  = ws + WS_AGG4;
    float* oadj  = ws + WS_OADJ;
    float* cab   = ws + WS_CA;
    float* csb   = ws + WS_CS;
    int*   bar   = (int*)(ws + WS_BAR);
    float* oraws = ws + WS_ORAWS;
    float* sss   = ws + WS_SSS;
    float* orawf = ws + WS_ORAWF;
    float* ssf   = ws + WS_SSF;

    __shared__ float h_lds[CHUNK][HP];     // 16.9 KB
    __shared__ float wpT[NC * HP];         // 8.4 KB
    __shared__ float s_lds[CHUNK][NC];     // 2 KB
    __shared__ float z_lds[CHUNK][4];
    __shared__ float c_lds[CHUNK];
    __shared__ float red[16 * 16 * 16];    // 16 KB
    __shared__ float shred[4];
    __shared__ int lastflag;

    int t = threadIdx.x;
    int b = blockIdx.x;
    int tid = b * NTHR + t;

    // ---------- Phase 1: in-degree counts (cnt zeroed by k_zero) ----------
    int e0 = tid * 2;
    bool v0 = e0 < E, v1 = (e0 + 1) < E;
    int2 es = v1 ? *reinterpret_cast<const int2*>(&ei[e0])
                 : make_int2(v0 ? ei[e0] : 0, 0);
    int2 ed = v1 ? *reinterpret_cast<const int2*>(&ei[E + e0])
                 : make_int2(v0 ? ei[E + e0] : 0, 0);
    if (v0) atomicAdd(&cnt[ed.x], 1.0f);
    if (v1) atomicAdd(&cnt[ed.y], 1.0f);
    gbar(bar);

    // ---------- Phase 2: agg4[d] += x[s] * dinv[s]  (dinv[d] deferred) ----------
    if (v0) {
        float di = rsqrtf(cnt[es.x] + 1.0f);
        float4 xv = reinterpret_cast<const float4*>(x)[es.x];
        atomicAdd(&agg4[ed.x * 4 + 0], di * xv.x);
        atomicAdd(&agg4[ed.x * 4 + 1], di * xv.y);
        atomicAdd(&agg4[ed.x * 4 + 2], di * xv.z);
        atomicAdd(&agg4[ed.x * 4 + 3], di * xv.w);
    }
    if (v1) {
        float di = rsqrtf(cnt[es.y] + 1.0f);
        float4 xv = reinterpret_cast<const float4*>(x)[es.y];
        atomicAdd(&agg4[ed.y * 4 + 0], di * xv.x);
        atomicAdd(&agg4[ed.y * 4 + 1], di * xv.y);
        atomicAdd(&agg4[ed.y * 4 + 2], di * xv.z);
        atomicAdd(&agg4[ed.y * 4 + 3], di * xv.w);
    }
    gbar(bar);

    // ---------- Phase 3: fused node pipeline (32 nodes per block) ----------
    {
        int base = b * CHUNK;
        #pragma unroll
        for (int r = 0; r < 8; ++r) {
            int idx = r * 256 + t;             // = f*16 + c
            wpT[(idx & 15) * HP + (idx >> 4)] = Wp[idx];
        }
        if (t < CHUNK) {
            float4 a  = reinterpret_cast<const float4*>(agg4)[base + t];
            float4 xv = reinterpret_cast<const float4*>(x)[base + t];
            float cn = cnt[base + t];
            c_lds[t] = cn;
            float di = rsqrtf(cn + 1.0f);
            // z = dinv * (agg4 + x * dinv)
            z_lds[t][0] = di * fmaf(xv.x, di, a.x);
            z_lds[t][1] = di * fmaf(xv.y, di, a.y);
            z_lds[t][2] = di * fmaf(xv.z, di, a.z);
            z_lds[t][3] = di * fmaf(xv.w, di, a.w);
        }
        __syncthreads();

        int f = t & 127;
        {
            float w0 = W1[f], w1 = W1[128 + f], w2 = W1[256 + f], w3 = W1[384 + f];
            float bb = b1[f];
            int n0 = t >> 7;
            #pragma unroll
            for (int r = 0; r < 16; ++r) {
                int n = n0 + r * 2;
                float v = fmaf(z_lds[n][0], w0, bb);
                v = fmaf(z_lds[n][1], w1, v);
                v = fmaf(z_lds[n][2], w2, v);
                v = fmaf(z_lds[n][3], w3, v);
                h_lds[n][f] = fmaxf(v, 0.0f);
            }
        }
        __syncthreads();

        int c = t & 15, g = t >> 4;
        const float4* wrow = reinterpret_cast<const float4*>(&wpT[c * HP]);
        #pragma unroll
        for (int pass = 0; pass < 2; ++pass) {
            int n = pass * 16 + g;
            const float4* hrow = reinterpret_cast<const float4*>(&h_lds[n][0]);
            float logit = bp[c];
            #pragma unroll 8
            for (int q = 0; q < 32; ++q) {
                float4 hv = hrow[q];
                float4 wv = wrow[q];
                logit = fmaf(hv.x, wv.x, logit);
                logit = fmaf(hv.y, wv.y, logit);
                logit = fmaf(hv.z, wv.z, logit);
                logit = fmaf(hv.w, wv.w, logit);
            }
            float m = logit;
            #pragma unroll
            for (int o = 8; o; o >>= 1) m = fmaxf(m, __shfl_xor(m, o, 16));
            float ex = expf(logit - m);
            float sum = ex;
            #pragma unroll
            for (int o = 8; o; o >>= 1) sum += __shfl_xor(sum, o, 16);
            float sv = ex / sum;
            s_lds[n][c] = sv;
            s_out[(base + n) * NC + c] = sv;
        }
        __syncthreads();

        float acc[8] = {0, 0, 0, 0, 0, 0, 0, 0};
        float acc_ss = 0.0f, acc_ca = 0.0f, acc_cs = 0.0f;
        int ch = t >> 7;
        int cS = t >> 4, kS = t & 15;
        #pragma unroll
        for (int i = 0; i < CHUNK; ++i) {
            float hv = h_lds[i][f];
            const float4* sv = reinterpret_cast<const float4*>(&s_lds[i][0]);
            float4 sa = sv[ch * 2], sb = sv[ch * 2 + 1];
            acc[0] = fmaf(sa.x, hv, acc[0]);
            acc[1] = fmaf(sa.y, hv, acc[1]);
            acc[2] = fmaf(sa.z, hv, acc[2]);
            acc[3] = fmaf(sa.w, hv, acc[3]);
            acc[4] = fmaf(sb.x, hv, acc[4]);
            acc[5] = fmaf(sb.y, hv, acc[5]);
            acc[6] = fmaf(sb.z, hv, acc[6]);
            acc[7] = fmaf(sb.w, hv, acc[7]);
            acc_ss = fmaf(s_lds[i][cS], s_lds[i][kS], acc_ss);
        }
        if (t < NC) {
            #pragma unroll
            for (int i = 0; i < CHUNK; ++i) {
                acc_ca = fmaf(s_lds[i][t], c_lds[i], acc_ca);
                acc_cs += s_lds[i][t];
            }
        }
        // per-block partials: PLAIN stores to slab (no fabric atomics)
        #pragma unroll
        for (int j = 0; j < 8; ++j)
            oraws[b * 2048 + (ch * 8 + j) * FH + f] = acc[j];
        sss[b * 256 + t] = acc_ss;
        if (t < NC) {
            int rep16 = b & 15;
            atomicAdd(&cab[rep16 * NC + t], acc_ca);
            atomicAdd(&csb[rep16 * NC + t], acc_cs);
        }
    }
    gbar(bar);

    // ---------- Phase 4a: out_adj[k][c] = sum_e s[src,k]*s[dst,c] ----------
    {
        int c = t & 15;
        int grp  = tid >> 4;
        int ngrp = (NBLK * NTHR) >> 4;     // 4096
        float acc[16];
        #pragma unroll
        for (int k = 0; k < 16; ++k) acc[k] = 0.0f;
        for (int e = grp; e < E; e += ngrp) {
            int sN = ei[e], dN = ei[E + e];
            float a = s_out[sN * NC + c];
            float bb = s_out[dN * NC + c];
            #pragma unroll
            for (int k = 0; k < 16; ++k)
                acc[k] = fmaf(__shfl(a, k, 16), bb, acc[k]);
        }
        int gl = t >> 4;
        #pragma unroll
        for (int k = 0; k < 16; ++k) red[gl * 256 + k * 16 + c] = acc[k];
        __syncthreads();
        int kk = t >> 4, cc = t & 15;
        float v = 0.0f;
        #pragma unroll
        for (int g2 = 0; g2 < 16; ++g2) v += red[g2 * 256 + kk * 16 + cc];
        atomicAdd(&oadj[(b & 3) * 256 + kk * 16 + cc], v);
    }

    // ---------- Phase 4b: slab tree-reductions (slabs complete at last gbar) ----------
    {
        // oraw: 8 columns per block, 32 threads per column
        int col = b * 8 + (t >> 5);
        int p = t & 31;
        float v = 0.0f;
        #pragma unroll
        for (int k = 0; k < 8; ++k) v += oraws[(p + 32 * k) * 2048 + col];
        #pragma unroll
        for (int o = 16; o; o >>= 1) v += __shfl_down(v, o, 32);
        if (p == 0) orawf[col] = v;
        // ss: element b, 256 partials
        float sv = sss[t * 256 + b];
        float ssum = bsum256(sv, shred);
        if (t == 0) ssf[b] = ssum;
    }

    // ---------- last-done block runs the epilogue ----------
    __syncthreads();
    if (t == 0) {
        __threadfence();
        int prev = __hip_atomic_fetch_add(&bar[BAR_DONE], 1, __ATOMIC_RELAXED,
                                          __HIP_MEMORY_SCOPE_AGENT);
        lastflag = (prev == NBLK - 1) ? 1 : 0;
        if (lastflag) __threadfence();     // acquire all blocks' results
    }
    __syncthreads();
    if (!lastflag) return;

    // ---------- Phase 5: losses + selu + log_softmax ----------
    {
        float Ef = (float)E;
        float s0 = 0.0f, s1 = 0.0f;
        if (t < 128) { s0 = ssf[t]; s1 = ssf[t + 128]; }
        float fro = sqrtf(bsum256(s0 * s0 + s1 * s1, shred));
        float d0 = 0.0f, d1 = 0.0f;
        if (t < 128) {
            d0 = s0 / fro - ((t % 17 == 0) ? 0.25f : 0.0f);
            d1 = s1 / fro - (((t + 128) % 17 == 0) ? 0.25f : 0.0f);
        }
        float ortho = sqrtf(bsum256(d0 * d0 + d1 * d1, shred));
        float tv = 0.0f, ca = 0.0f, cs = 0.0f;
        if (t < NC) {
            #pragma unroll
            for (int r = 0; r < 4; ++r) tv += oadj[r * 256 + t * 17];
            #pragma unroll
            for (int r = 0; r < 16; ++r) { ca += cab[r * NC + t]; cs += csb[r * NC + t]; }
        }
        float tr_adj = bsum256(tv, shred);
        float tr_n = bsum256(ca * ca, shred) / Ef;
        float spectral = -(tr_adj - tr_n) / Ef;
        float cluster = sqrtf(bsum256(cs * cs, shred)) / (float)NN * 4.0f - 1.0f;
        if (t == 0) d_out[NC * FH] = spectral + ortho + cluster;
        for (int cR = 0; cR < NC; ++cR) {
            float v = 0.0f;
            if (t < 128) v = selu_f(orawf[cR * FH + t]);
            float mx = bmax256(t < 128 ? v : -1e30f, shred);
            float e = (t < 128) ? expf(v - mx) : 0.0f;
            float sm = bsum256(e, shred);
            if (t < 128) d_out[cR * FH + t] = v - mx - logf(sm);
        }
    }
}

extern "C" void kernel_launch(void* const* d_in, const int* in_sizes, int n_in,
                              void* d_out, int out_size, void* d_ws, size_t ws_size,
                              hipStream_t stream) {
    const float* x  = (const float*)d_in[0];
    const float* W1 = (const float*)d_in[1];
    const float* b1 = (const float*)d_in[2];
    const float* Wp = (const float*)d_in[3];
    const float* bp = (const float*)d_in[4];
    const int*   ei = (const int*)d_in[5];
    int E = in_sizes[5] / 2;

    float* ws  = (float*)d_ws;
    float* out = (float*)d_out;           // [0..2047] log_softmax, [2048] loss
    float* s   = out + NC * FH + 1;       // [2049..] assignments (8192 x 16)

    k_zero<<<(WS_ZERO_FLOATS / 4 + 255) / 256, 256, 0, stream>>>((float4*)d_ws);
    k_mega<<<NBLK, NTHR, 0, stream>>>(x, W1, b1, Wp, bp, ei, ws, s, out, E);
}

// Round 9
// 93.543 us; speedup vs baseline: 1.2547x; 1.2547x over previous
//
#include <hip/hip_runtime.h>
#include <math.h>

#define NN 8192      // nodes
#define FH 128       // hidden
#define NC 16        // clusters
#define HP 132       // padded LDS row
#define CHUNK 32     // nodes per block in node phase

// ---------------- workspace layout (floats) ----------------
#define WS_CNT   0          // [8192]   zeroed by k_zero_cnt
#define WS_AGG4  8192       // [32768]  zeroed by k_degree
// accumulator region zeroed by k_edge_agg (blocks 0-11):
#define WS_ORAW  40960      // 4 x 2048 replicas
#define WS_SS    49152      // 4 x 256 replicas
#define WS_CA    50176      // 16 x 16 replicas
#define WS_CS    50432      // 16 x 16 replicas
#define WS_OADJ  50688      // 8 x 256 replicas
#define WS_DONE  52736      // [128] ints (done counter)
#define WS_ACC_BEGIN_F4 10240   // 40960/4
#define WS_ACC_COUNT_F4 2976    // (52864-40960)/4

// ---------------- K1: zero cnt ----------------
__global__ __launch_bounds__(256) void k_zero_cnt(float4* __restrict__ ws) {
    int i = blockIdx.x * blockDim.x + threadIdx.x;   // 8 blocks -> 2048 f4
    if (i < NN / 4) ws[i] = make_float4(0.f, 0.f, 0.f, 0.f);
}

// ---------------- K2: in-degree counts + zero agg4 ----------------
__global__ __launch_bounds__(256) void k_degree(const int* __restrict__ ei,
                                                float* __restrict__ ws, int E) {
    int t = threadIdx.x, b = blockIdx.x;
    if (t < 16)   // zero agg4: 512 blocks x 16 float4 = 32768 floats
        reinterpret_cast<float4*>(ws)[NN / 4 + b * 16 + t] =
            make_float4(0.f, 0.f, 0.f, 0.f);
    int e = b * 256 + t;
    if (e < E) atomicAdd(&ws[WS_CNT + ei[E + e]], 1.0f);
}

// ---------------- K3: agg4[d] += x[s]*dinv[s] + zero accumulators ----------------
__global__ __launch_bounds__(256) void k_edge_agg(const int* __restrict__ ei,
                                                  const float* __restrict__ x,
                                                  float* __restrict__ ws, int E) {
    int t = threadIdx.x, b = blockIdx.x;
    if (b < 12) {   // zero oraw/ss/ca/cs/oadj/done region
        int i = b * 256 + t;
        if (i < WS_ACC_COUNT_F4)
            reinterpret_cast<float4*>(ws)[WS_ACC_BEGIN_F4 + i] =
                make_float4(0.f, 0.f, 0.f, 0.f);
    }
    int e = b * 256 + t;
    if (e >= E) return;
    int s = ei[e], d = ei[E + e];
    float di = rsqrtf(ws[WS_CNT + s] + 1.0f);
    float4 xv = reinterpret_cast<const float4*>(x)[s];
    float* agg4 = ws + WS_AGG4;
    atomicAdd(&agg4[d * 4 + 0], di * xv.x);
    atomicAdd(&agg4[d * 4 + 1], di * xv.y);
    atomicAdd(&agg4[d * 4 + 2], di * xv.z);
    atomicAdd(&agg4[d * 4 + 3], di * xv.w);
}

// ---------------- K4: fused node pipeline (round-2/3 proven version) ----------------
__global__ __launch_bounds__(256) void k_node(const float* __restrict__ x,
                                              const float* __restrict__ W1,
                                              const float* __restrict__ b1,
                                              const float* __restrict__ Wp,
                                              const float* __restrict__ bp,
                                              float* __restrict__ ws,
                                              float* __restrict__ s_out) {
    float* cnt  = ws + WS_CNT;
    float* agg4 = ws + WS_AGG4;
    float* oraw = ws + WS_ORAW;
    float* ssb  = ws + WS_SS;
    float* cab  = ws + WS_CA;
    float* csb  = ws + WS_CS;

    __shared__ float h_lds[CHUNK][HP];
    __shared__ float wpT[NC * HP];
    __shared__ float s_lds[CHUNK][NC];
    __shared__ float z_lds[CHUNK][4];
    __shared__ float c_lds[CHUNK];
    int t = threadIdx.x;
    int b = blockIdx.x;
    int base = b * CHUNK;

    #pragma unroll
    for (int r = 0; r < 8; ++r) {
        int idx = r * 256 + t;             // = f*16 + c
        wpT[(idx & 15) * HP + (idx >> 4)] = Wp[idx];
    }
    if (t < CHUNK) {
        float4 a  = reinterpret_cast<const float4*>(agg4)[base + t];
        float4 xv = reinterpret_cast<const float4*>(x)[base + t];
        float cn = cnt[base + t];
        c_lds[t] = cn;
        float di = rsqrtf(cn + 1.0f);
        z_lds[t][0] = di * fmaf(xv.x, di, a.x);
        z_lds[t][1] = di * fmaf(xv.y, di, a.y);
        z_lds[t][2] = di * fmaf(xv.z, di, a.z);
        z_lds[t][3] = di * fmaf(xv.w, di, a.w);
    }
    __syncthreads();

    int f = t & 127;
    {
        float w0 = W1[f], w1 = W1[128 + f], w2 = W1[256 + f], w3 = W1[384 + f];
        float bb = b1[f];
        int n0 = t >> 7;
        #pragma unroll
        for (int r = 0; r < 16; ++r) {
            int n = n0 + r * 2;
            float v = fmaf(z_lds[n][0], w0, bb);
            v = fmaf(z_lds[n][1], w1, v);
            v = fmaf(z_lds[n][2], w2, v);
            v = fmaf(z_lds[n][3], w3, v);
            h_lds[n][f] = fmaxf(v, 0.0f);
        }
    }
    __syncthreads();

    int c = t & 15, g = t >> 4;
    const float4* wrow = reinterpret_cast<const float4*>(&wpT[c * HP]);
    #pragma unroll
    for (int pass = 0; pass < 2; ++pass) {
        int n = pass * 16 + g;
        const float4* hrow = reinterpret_cast<const float4*>(&h_lds[n][0]);
        float logit = bp[c];
        #pragma unroll 8
        for (int q = 0; q < 32; ++q) {
            float4 hv = hrow[q];
            float4 wv = wrow[q];
            logit = fmaf(hv.x, wv.x, logit);
            logit = fmaf(hv.y, wv.y, logit);
            logit = fmaf(hv.z, wv.z, logit);
            logit = fmaf(hv.w, wv.w, logit);
        }
        float m = logit;
        #pragma unroll
        for (int o = 8; o; o >>= 1) m = fmaxf(m, __shfl_xor(m, o, 16));
        float ex = expf(logit - m);
        float sum = ex;
        #pragma unroll
        for (int o = 8; o; o >>= 1) sum += __shfl_xor(sum, o, 16);
        float sv = ex / sum;
        s_lds[n][c] = sv;
        s_out[(base + n) * NC + c] = sv;
    }
    __syncthreads();

    float acc[8] = {0, 0, 0, 0, 0, 0, 0, 0};
    float acc_ss = 0.0f, acc_ca = 0.0f, acc_cs = 0.0f;
    int ch = t >> 7;
    int cS = t >> 4, kS = t & 15;
    #pragma unroll
    for (int i = 0; i < CHUNK; ++i) {
        float hv = h_lds[i][f];
        const float4* sv = reinterpret_cast<const float4*>(&s_lds[i][0]);
        float4 sa = sv[ch * 2], sb = sv[ch * 2 + 1];
        acc[0] = fmaf(sa.x, hv, acc[0]);
        acc[1] = fmaf(sa.y, hv, acc[1]);
        acc[2] = fmaf(sa.z, hv, acc[2]);
        acc[3] = fmaf(sa.w, hv, acc[3]);
        acc[4] = fmaf(sb.x, hv, acc[4]);
        acc[5] = fmaf(sb.y, hv, acc[5]);
        acc[6] = fmaf(sb.z, hv, acc[6]);
        acc[7] = fmaf(sb.w, hv, acc[7]);
        acc_ss = fmaf(s_lds[i][cS], s_lds[i][kS], acc_ss);
    }
    if (t < NC) {
        #pragma unroll
        for (int i = 0; i < CHUNK; ++i) {
            acc_ca = fmaf(s_lds[i][t], c_lds[i], acc_ca);
            acc_cs += s_lds[i][t];
        }
    }
    int rep = b & 3;
    #pragma unroll
    for (int j = 0; j < 8; ++j)
        atomicAdd(&oraw[rep * 2048 + (ch * 8 + j) * FH + f], acc[j]);
    atomicAdd(&ssb[rep * 256 + cS * NC + kS], acc_ss);
    if (t < NC) {
        int rep16 = b & 15;
        atomicAdd(&cab[rep16 * NC + t], acc_ca);
        atomicAdd(&csb[rep16 * NC + t], acc_cs);
    }
}

// ---------------- epilogue helpers (256 threads) ----------------
__device__ __forceinline__ float bsum256(float v, float* sh) {
    #pragma unroll
    for (int o = 32; o; o >>= 1) v += __shfl_down(v, o, 64);
    if ((threadIdx.x & 63) == 0) sh[threadIdx.x >> 6] = v;
    __syncthreads();
    float r = sh[0] + sh[1] + sh[2] + sh[3];
    __syncthreads();
    return r;
}
__device__ __forceinline__ float bmax256(float v, float* sh) {
    #pragma unroll
    for (int o = 32; o; o >>= 1) v = fmaxf(v, __shfl_down(v, o, 64));
    if ((threadIdx.x & 63) == 0) sh[threadIdx.x >> 6] = v;
    __syncthreads();
    float r = fmaxf(fmaxf(sh[0], sh[1]), fmaxf(sh[2], sh[3]));
    __syncthreads();
    return r;
}
__device__ __forceinline__ float selu_f(float x) {
    const float a = 1.6732632423543772f, sc = 1.0507009873554805f;
    return sc * (x > 0.0f ? x : a * (expf(x) - 1.0f));
}

// ---------------- K5: out_adj + fused losses/log_softmax epilogue ----------------
#define ADJ_BLOCKS 512
__global__ __launch_bounds__(256) void k_adj_final(const int* __restrict__ ei,
                                                   const float* __restrict__ s,
                                                   float* __restrict__ ws,
                                                   float* __restrict__ d_out, int E) {
    float* oraw = ws + WS_ORAW;
    float* ssb  = ws + WS_SS;
    float* cab  = ws + WS_CA;
    float* csb  = ws + WS_CS;
    float* oadj = ws + WS_OADJ;
    int*   done = (int*)(ws + WS_DONE);

    __shared__ float red[16 * 16 * 16];    // 16 KB
    __shared__ float shred[4];
    __shared__ int lastflag;

    int t = threadIdx.x;
    int b = blockIdx.x;

    {
        int c = t & 15;
        int grp  = (b * 256 + t) >> 4;
        int ngrp = (ADJ_BLOCKS * 256) >> 4;     // 8192 -> 16 edges/group
        float acc[16];
        #pragma unroll
        for (int k = 0; k < 16; ++k) acc[k] = 0.0f;
        for (int e = grp; e < E; e += ngrp) {
            int sN = ei[e], dN = ei[E + e];
            float a = s[sN * NC + c];
            float bb = s[dN * NC + c];
            #pragma unroll
            for (int k = 0; k < 16; ++k)
                acc[k] = fmaf(__shfl(a, k, 16), bb, acc[k]);
        }
        int gl = t >> 4;
        #pragma unroll
        for (int k = 0; k < 16; ++k) red[gl * 256 + k * 16 + c] = acc[k];
        __syncthreads();
        int kk = t >> 4, cc = t & 15;
        float v = 0.0f;
        #pragma unroll
        for (int g2 = 0; g2 < 16; ++g2) v += red[g2 * 256 + kk * 16 + cc];
        atomicAdd(&oadj[(b & 7) * 256 + kk * 16 + cc], v);
    }

    // ---- last-done block runs the epilogue ----
    __syncthreads();
    if (t == 0) {
        __threadfence();
        int prev = __hip_atomic_fetch_add(&done[0], 1, __ATOMIC_RELAXED,
                                          __HIP_MEMORY_SCOPE_AGENT);
        lastflag = (prev == ADJ_BLOCKS - 1) ? 1 : 0;
        if (lastflag) __threadfence();     // acquire all blocks' results
    }
    __syncthreads();
    if (!lastflag) return;

    {
        float Ef = (float)E;
        float s0 = 0.0f, s1 = 0.0f;
        if (t < 128) {
            #pragma unroll
            for (int r = 0; r < 4; ++r) {
                s0 += ssb[r * 256 + t];
                s1 += ssb[r * 256 + 128 + t];
            }
        }
        float fro = sqrtf(bsum256(s0 * s0 + s1 * s1, shred));
        float d0 = 0.0f, d1 = 0.0f;
        if (t < 128) {
            d0 = s0 / fro - ((t % 17 == 0) ? 0.25f : 0.0f);
            d1 = s1 / fro - (((t + 128) % 17 == 0) ? 0.25f : 0.0f);
        }
        float ortho = sqrtf(bsum256(d0 * d0 + d1 * d1, shred));
        float tv = 0.0f, ca = 0.0f, cs = 0.0f;
        if (t < NC) {
            #pragma unroll
            for (int r = 0; r < 8; ++r) tv += oadj[r * 256 + t * 17];
            #pragma unroll
            for (int r = 0; r < 16; ++r) { ca += cab[r * NC + t]; cs += csb[r * NC + t]; }
        }
        float tr_adj = bsum256(tv, shred);
        float tr_n = bsum256(ca * ca, shred) / Ef;
        float spectral = -(tr_adj - tr_n) / Ef;
        float cluster = sqrtf(bsum256(cs * cs, shred)) / (float)NN * 4.0f - 1.0f;
        if (t == 0) d_out[NC * FH] = spectral + ortho + cluster;
        for (int cR = 0; cR < NC; ++cR) {
            float v = 0.0f;
            if (t < 128) {
                #pragma unroll
                for (int r = 0; r < 4; ++r) v += oraw[r * 2048 + cR * FH + t];
                v = selu_f(v);
            }
            float mx = bmax256(t < 128 ? v : -1e30f, shred);
            float e = (t < 128) ? expf(v - mx) : 0.0f;
            float sm = bsum256(e, shred);
            if (t < 128) d_out[cR * FH + t] = v - mx - logf(sm);
        }
    }
}

extern "C" void kernel_launch(void* const* d_in, const int* in_sizes, int n_in,
                              void* d_out, int out_size, void* d_ws, size_t ws_size,
                              hipStream_t stream) {
    const float* x  = (const float*)d_in[0];
    const float* W1 = (const float*)d_in[1];
    const float* b1 = (const float*)d_in[2];
    const float* Wp = (const float*)d_in[3];
    const float* bp = (const float*)d_in[4];
    const int*   ei = (const int*)d_in[5];
    int E = in_sizes[5] / 2;

    float* ws  = (float*)d_ws;
    float* out = (float*)d_out;           // [0..2047] log_softmax, [2048] loss
    float* s   = out + NC * FH + 1;       // [2049..] assignments (8192 x 16)

    k_zero_cnt<<<8, 256, 0, stream>>>((float4*)d_ws);
    k_degree  <<<(E + 255) / 256, 256, 0, stream>>>(ei, ws, E);
    k_edge_agg<<<(E + 255) / 256, 256, 0, stream>>>(ei, x, ws, E);
    k_node    <<<NN / CHUNK, 256, 0, stream>>>(x, W1, b1, Wp, bp, ws, s);
    k_adj_final<<<ADJ_BLOCKS, 256, 0, stream>>>(ei, s, ws, out, E);
}